// Round 1
// baseline (20.735 us; speedup 1.0000x reference)
//
#include <hip/hip_runtime.h>

// Problem: x,y float32 shape (B=2, C=1, D=32, H=128, W=128).
// out = mean over [B,C,D,3,H,3,W,3] of |(x_c - x_n) - (y_c - y_n)|
//     = mean of |d_c - d_n| with d = x - y, zero-padded neighbors.
constexpr int Dd = 32, Hh = 128, Ww = 128, Bv = 2;
constexpr int NVOX = Bv * Dd * Hh * Ww;      // 1,048,576 voxels
constexpr int BLK = 256;
constexpr int NB_LOSS = NVOX / BLK;          // 4096 blocks, 1 thread/voxel

// ---- Kernel A: d = x - y (float4 vectorized) ----
__global__ void diff_kernel(const float4* __restrict__ x,
                            const float4* __restrict__ y,
                            float4* __restrict__ d) {
    int i = blockIdx.x * blockDim.x + threadIdx.x;
    float4 a = x[i];
    float4 b = y[i];
    d[i] = make_float4(a.x - b.x, a.y - b.y, a.z - b.z, a.w - b.w);
}

// ---- Kernel B: per-voxel 27-neighbor |d_c - d_n| sum, block partial ----
__global__ void __launch_bounds__(BLK)
loss_kernel(const float* __restrict__ d, float* __restrict__ partials) {
    const int i = blockIdx.x * BLK + threadIdx.x;
    // Layout: i = ((b*Dd + dz)*Hh + hy)*Ww + wx ; C==1, b doesn't matter for
    // neighbor bounds because dz wraps within [0,Dd) per volume.
    const int wx = i & (Ww - 1);
    const int hy = (i >> 7) & (Hh - 1);
    const int dz = (i >> 14) & (Dd - 1);

    const float dc = d[i];
    float s = 0.0f;
#pragma unroll
    for (int kd = -1; kd <= 1; ++kd) {
        const bool zin = (unsigned)(dz + kd) < (unsigned)Dd;
#pragma unroll
        for (int kh = -1; kh <= 1; ++kh) {
            const bool yin = zin && ((unsigned)(hy + kh) < (unsigned)Hh);
#pragma unroll
            for (int kw = -1; kw <= 1; ++kw) {
                const bool in = yin && ((unsigned)(wx + kw) < (unsigned)Ww);
                const int j = i + (kd * Hh + kh) * Ww + kw;
                const float dn = in ? d[j] : 0.0f;   // zero padding
                s += fabsf(dc - dn);                 // center term adds 0
            }
        }
    }

    // wave64 reduce
#pragma unroll
    for (int off = 32; off > 0; off >>= 1)
        s += __shfl_down(s, off, 64);

    __shared__ float smem[BLK / 64];
    const int lane = threadIdx.x & 63;
    const int wid  = threadIdx.x >> 6;
    if (lane == 0) smem[wid] = s;
    __syncthreads();
    if (threadIdx.x == 0) {
        float t = 0.0f;
#pragma unroll
        for (int w = 0; w < BLK / 64; ++w) t += smem[w];
        partials[blockIdx.x] = t;
    }
}

// ---- Kernel C: reduce 4096 partials, scale, write scalar out ----
__global__ void __launch_bounds__(BLK)
finish_kernel(const float* __restrict__ partials, float* __restrict__ out) {
    double s = 0.0;
    for (int i = threadIdx.x; i < NB_LOSS; i += BLK)
        s += (double)partials[i];
#pragma unroll
    for (int off = 32; off > 0; off >>= 1)
        s += __shfl_down(s, off, 64);

    __shared__ double smem[BLK / 64];
    const int lane = threadIdx.x & 63;
    const int wid  = threadIdx.x >> 6;
    if (lane == 0) smem[wid] = s;
    __syncthreads();
    if (threadIdx.x == 0) {
        double t = 0.0;
#pragma unroll
        for (int w = 0; w < BLK / 64; ++w) t += smem[w];
        out[0] = (float)(t / (27.0 * (double)NVOX));
    }
}

extern "C" void kernel_launch(void* const* d_in, const int* in_sizes, int n_in,
                              void* d_out, int out_size, void* d_ws, size_t ws_size,
                              hipStream_t stream) {
    const float* x = (const float*)d_in[0];
    const float* y = (const float*)d_in[1];
    float* d        = (float*)d_ws;          // NVOX floats = 4 MiB
    float* partials = d + NVOX;              // 4096 floats
    float* out      = (float*)d_out;

    diff_kernel<<<NVOX / 4 / BLK, BLK, 0, stream>>>(
        (const float4*)x, (const float4*)y, (float4*)d);
    loss_kernel<<<NB_LOSS, BLK, 0, stream>>>(d, partials);
    finish_kernel<<<1, BLK, 0, stream>>>(partials, out);
}

// Round 2
// 13.493 us; speedup vs baseline: 1.5367x; 1.5367x over previous
//
#include <hip/hip_runtime.h>

// x,y float32 (B=2, C=1, D=32, H=128, W=128).
// out = mean over 27-neighborhood of |d_c - d_n|, d = x - y, zero-padded.
constexpr int Dd = 32, Hh = 128, Ww = 128, Bv = 2;
constexpr int NVOX = Bv * Dd * Hh * Ww;      // 1,048,576
constexpr int BLK = 256;

// Tile geometry: each block owns TD x TH x TW voxels, stages the (TD+2)x(TH+2)x(TW+2)
// halo of d = x - y in LDS, then does the 27-neighbor |d_c - d_n| sum with a
// register sliding window along W.
constexpr int TD = 4, TH = 8, TW = 64;
constexpr int LZ = TD + 2;                   // 6
constexpr int LY = TH + 2;                   // 10
constexpr int LWS = TW + 3;                  // 67: odd stride -> benign bank pattern
constexpr int ZT = Dd / TD;                  // 8
constexpr int YT = Hh / TH;                  // 16
constexpr int WT = Ww / TW;                  // 2
constexpr int NBLK = Bv * ZT * YT * WT;      // 512 blocks, 2/CU
constexpr int LDS_N = LZ * LY * LWS;         // 4020 floats = 16,080 B
constexpr int WRUN = TW / 8;                 // 8 voxels per thread along W

__global__ void __launch_bounds__(BLK)
fused_kernel(const float* __restrict__ x, const float* __restrict__ y,
             float* __restrict__ partials) {
    __shared__ float lds[LDS_N];

    int bid = blockIdx.x;
    const int wt  = bid & (WT - 1); bid >>= 1;
    const int yt  = bid & (YT - 1); bid >>= 4;
    const int zt  = bid & (ZT - 1); bid >>= 3;
    const int vol = bid;                      // 0..1

    const int z0  = zt * TD;
    const int y0  = yt * TH;
    const int w0g = wt * TW;
    const size_t volOff = (size_t)vol * Dd * Hh * Ww;

    // ---- stage d = x - y halo tile into LDS (zero outside the volume) ----
    for (int e = threadIdx.x; e < LDS_N; e += BLK) {
        const int lw = e % LWS;
        const int t  = e / LWS;
        const int ly = t % LY;
        const int lz = t / LY;
        float v = 0.0f;
        const int gw = w0g + lw - 1;
        const int gy = y0 + ly - 1;
        const int gz = z0 + lz - 1;
        if (lw < TW + 2 &&
            (unsigned)gw < (unsigned)Ww &&
            (unsigned)gy < (unsigned)Hh &&
            (unsigned)gz < (unsigned)Dd) {
            const size_t g = volOff + ((size_t)gz * Hh + gy) * Ww + gw;
            v = x[g] - y[g];
        }
        lds[e] = v;
    }
    __syncthreads();

    // ---- 27-neighbor sum; thread -> (row rr of TD*TH=32, w-segment of 8) ----
    const int rr  = threadIdx.x & 31;
    const int seg = threadIdx.x >> 5;         // 0..7
    const int lz  = rr >> 3;                  // 0..3
    const int ly  = rr & 7;                   // 0..7
    const int w0  = seg * WRUN;

    const float* crow = &lds[((lz + 1) * LY + (ly + 1)) * LWS + 1 + w0];
    float c[WRUN];
#pragma unroll
    for (int j = 0; j < WRUN; ++j) c[j] = crow[j];

    float s = 0.0f;
#pragma unroll
    for (int kd = 0; kd < 3; ++kd) {
#pragma unroll
        for (int kh = 0; kh < 3; ++kh) {
            const float* row = &lds[((lz + kd) * LY + (ly + kh)) * LWS + 1 + w0];
            float wm = row[-1];
            float wc = row[0];
#pragma unroll
            for (int j = 0; j < WRUN; ++j) {
                const float wp = row[j + 1];
                s += fabsf(c[j] - wm) + fabsf(c[j] - wc) + fabsf(c[j] - wp);
                wm = wc; wc = wp;
            }
        }
    }

    // ---- block reduction ----
#pragma unroll
    for (int off = 32; off > 0; off >>= 1)
        s += __shfl_down(s, off, 64);

    __shared__ float smem[BLK / 64];
    const int lane = threadIdx.x & 63;
    const int wid  = threadIdx.x >> 6;
    if (lane == 0) smem[wid] = s;
    __syncthreads();
    if (threadIdx.x == 0) {
        float t = 0.0f;
#pragma unroll
        for (int w = 0; w < BLK / 64; ++w) t += smem[w];
        partials[blockIdx.x] = t;
    }
}

__global__ void __launch_bounds__(BLK)
finish_kernel(const float* __restrict__ partials, float* __restrict__ out) {
    double s = 0.0;
    for (int i = threadIdx.x; i < NBLK; i += BLK)
        s += (double)partials[i];
#pragma unroll
    for (int off = 32; off > 0; off >>= 1)
        s += __shfl_down(s, off, 64);

    __shared__ double smem[BLK / 64];
    const int lane = threadIdx.x & 63;
    const int wid  = threadIdx.x >> 6;
    if (lane == 0) smem[wid] = s;
    __syncthreads();
    if (threadIdx.x == 0) {
        double t = 0.0;
#pragma unroll
        for (int w = 0; w < BLK / 64; ++w) t += smem[w];
        out[0] = (float)(t / (27.0 * (double)NVOX));
    }
}

extern "C" void kernel_launch(void* const* d_in, const int* in_sizes, int n_in,
                              void* d_out, int out_size, void* d_ws, size_t ws_size,
                              hipStream_t stream) {
    const float* x = (const float*)d_in[0];
    const float* y = (const float*)d_in[1];
    float* partials = (float*)d_ws;           // NBLK floats
    float* out      = (float*)d_out;

    fused_kernel<<<NBLK, BLK, 0, stream>>>(x, y, partials);
    finish_kernel<<<1, BLK, 0, stream>>>(partials, out);
}